// Round 1
// baseline (580.256 us; speedup 1.0000x reference)
//
#include <hip/hip_runtime.h>

// COO SpMM: out[b,d] = sum_{e: row[e]==d} vals[e] * x[b, col[e]] + bias[d]
// B=64 (one wave), NUM_SRC=NUM_DST=100000, NNZ=3.2M, all fp32.
//
// Plan: device-side CSR build (hist -> scan -> scatter of packed (val,col)
// pairs), then one-wave-per-destination gather-accumulate from xT, then
// transpose + bias into the (B, NUM_DST) output.

#define WAVE 64

// ---------- transpose x (B=64, nsrc) -> xT (nsrc, 64) ----------
__global__ __launch_bounds__(1024) void transpose_x_kernel(
    const float* __restrict__ x, float* __restrict__ xT, int nsrc) {
  __shared__ float tile[64][65];
  int s0 = blockIdx.x * 64;
  int tx = threadIdx.x;  // 0..63
  int ty = threadIdx.y;  // 0..15
#pragma unroll
  for (int i = 0; i < 4; ++i) {
    int b = ty + i * 16;
    int s = s0 + tx;
    tile[tx][b] = (s < nsrc) ? x[(size_t)b * nsrc + s] : 0.f;
  }
  __syncthreads();
#pragma unroll
  for (int i = 0; i < 4; ++i) {
    int sl = ty + i * 16;
    int s = s0 + sl;
    if (s < nsrc) xT[(size_t)s * 64 + tx] = tile[sl][tx];
  }
}

// ---------- histogram of destinations ----------
__global__ __launch_bounds__(256) void hist_kernel(
    const int* __restrict__ row, int* __restrict__ counts, int nnz) {
  int stride = gridDim.x * blockDim.x;
  for (int i = blockIdx.x * blockDim.x + threadIdx.x; i < nnz; i += stride)
    atomicAdd(&counts[row[i]], 1);
}

// ---------- exclusive scan (3 kernels; n <= 512*256) ----------
__global__ __launch_bounds__(256) void scan_block_kernel(
    const int* __restrict__ counts, int* __restrict__ excl,
    int* __restrict__ blockSums, int n) {
  __shared__ int tmp[256];
  int gid = blockIdx.x * 256 + threadIdx.x;
  int v = (gid < n) ? counts[gid] : 0;
  tmp[threadIdx.x] = v;
  __syncthreads();
#pragma unroll
  for (int ofs = 1; ofs < 256; ofs <<= 1) {
    int t = (threadIdx.x >= ofs) ? tmp[threadIdx.x - ofs] : 0;
    __syncthreads();
    tmp[threadIdx.x] += t;
    __syncthreads();
  }
  if (gid < n) excl[gid] = tmp[threadIdx.x] - v;  // exclusive
  if (threadIdx.x == 255) blockSums[blockIdx.x] = tmp[255];
}

__global__ __launch_bounds__(512) void scan_sums_kernel(int* blockSums, int nb) {
  __shared__ int tmp[512];
  int v = (threadIdx.x < nb) ? blockSums[threadIdx.x] : 0;
  tmp[threadIdx.x] = v;
  __syncthreads();
#pragma unroll
  for (int ofs = 1; ofs < 512; ofs <<= 1) {
    int t = (threadIdx.x >= ofs) ? tmp[threadIdx.x - ofs] : 0;
    __syncthreads();
    tmp[threadIdx.x] += t;
    __syncthreads();
  }
  if (threadIdx.x < nb) blockSums[threadIdx.x] = tmp[threadIdx.x] - v;  // exclusive
}

__global__ __launch_bounds__(256) void add_offsets_kernel(
    int* __restrict__ excl, const int* __restrict__ blockSums, int n, int total) {
  int gid = blockIdx.x * 256 + threadIdx.x;
  if (gid < n) excl[gid] += blockSums[blockIdx.x];
  if (gid == 0) excl[n] = total;
}

// ---------- scatter edges into CSR order as packed (val, col) ----------
__global__ __launch_bounds__(256) void scatter_kernel(
    const int* __restrict__ row, const int* __restrict__ col,
    const float* __restrict__ vals, const int* __restrict__ base,
    int* __restrict__ cursor, float2* __restrict__ pairs, int nnz) {
  int stride = gridDim.x * blockDim.x;
  for (int i = blockIdx.x * blockDim.x + threadIdx.x; i < nnz; i += stride) {
    int d = row[i];
    int pos = base[d] + atomicAdd(&cursor[d], 1);
    pairs[pos] = make_float2(vals[i], __int_as_float(col[i]));
  }
}

// ---------- SpMM: one wave per destination row ----------
__global__ __launch_bounds__(256) void spmm_kernel(
    const float2* __restrict__ pairs, const int* __restrict__ base,
    const float* __restrict__ xT, float* __restrict__ accT, int ndst) {
  int wave = blockIdx.x * (blockDim.x >> 6) + (threadIdx.x >> 6);
  int lane = threadIdx.x & 63;
  if (wave >= ndst) return;
  int start = base[wave];
  int end = base[wave + 1];
  float acc = 0.f;
  int j = start;
  for (; j + 1 < end; j += 2) {
    float2 p0 = pairs[j];
    float2 p1 = pairs[j + 1];
    int c0 = __float_as_int(p0.y);
    int c1 = __float_as_int(p1.y);
    acc += p0.x * xT[(size_t)c0 * 64 + lane];
    acc += p1.x * xT[(size_t)c1 * 64 + lane];
  }
  if (j < end) {
    float2 p = pairs[j];
    acc += p.x * xT[(size_t)__float_as_int(p.y) * 64 + lane];
  }
  accT[(size_t)wave * 64 + lane] = acc;
}

// ---------- accT (ndst, 64) + bias -> out (64, ndst) ----------
__global__ __launch_bounds__(1024) void write_out_kernel(
    const float* __restrict__ accT, const float* __restrict__ bias,
    float* __restrict__ out, int ndst) {
  __shared__ float tile[64][65];
  int d0 = blockIdx.x * 64;
  int tx = threadIdx.x;
  int ty = threadIdx.y;
#pragma unroll
  for (int i = 0; i < 4; ++i) {
    int dl = ty + i * 16;
    int d = d0 + dl;
    tile[tx][dl] = (d < ndst) ? accT[(size_t)d * 64 + tx] : 0.f;  // tx = b
  }
  __syncthreads();
#pragma unroll
  for (int i = 0; i < 4; ++i) {
    int b = ty + i * 16;
    int d = d0 + tx;
    if (d < ndst) out[(size_t)b * ndst + d] = tile[b][tx] + bias[d];
  }
}

extern "C" void kernel_launch(void* const* d_in, const int* in_sizes, int n_in,
                              void* d_out, int out_size, void* d_ws, size_t ws_size,
                              hipStream_t stream) {
  const float* x = (const float*)d_in[0];
  const float* vals = (const float*)d_in[1];
  const float* bias = (const float*)d_in[2];
  const int* row = (const int*)d_in[3];
  const int* col = (const int*)d_in[4];
  float* out = (float*)d_out;

  const int nnz = in_sizes[1];
  const int ndst = in_sizes[2];
  const int B = out_size / ndst;  // == 64 == WAVE for this problem
  const int nsrc = in_sizes[0] / B;

  // workspace layout (256B-aligned chunks)
  size_t off = 0;
  auto take = [&](size_t bytes) {
    void* p = (char*)d_ws + off;
    off += (bytes + 255) & ~(size_t)255;
    return p;
  };
  float* xT = (float*)take((size_t)nsrc * 64 * 4);
  float2* pairs = (float2*)take((size_t)nnz * 8);
  float* accT = (float*)take((size_t)ndst * 64 * 4);
  int* base = (int*)take((size_t)(ndst + 1) * 4);
  int* counts = (int*)take((size_t)ndst * 4);
  int* cursor = (int*)take((size_t)ndst * 4);
  int* blockSums = (int*)take(512 * 4);
  (void)ws_size;

  hipMemsetAsync(counts, 0, (size_t)ndst * 4, stream);
  hipMemsetAsync(cursor, 0, (size_t)ndst * 4, stream);

  // 1. transpose x -> xT
  {
    dim3 blk(64, 16);
    int grid = (nsrc + 63) / 64;
    transpose_x_kernel<<<grid, blk, 0, stream>>>(x, xT, nsrc);
  }
  // 2. histogram
  hist_kernel<<<2048, 256, 0, stream>>>(row, counts, nnz);
  // 3. exclusive scan counts -> base
  {
    int nb = (ndst + 255) / 256;  // 391 <= 512
    scan_block_kernel<<<nb, 256, 0, stream>>>(counts, base, blockSums, ndst);
    scan_sums_kernel<<<1, 512, 0, stream>>>(blockSums, nb);
    add_offsets_kernel<<<nb, 256, 0, stream>>>(base, blockSums, ndst, nnz);
  }
  // 4. scatter edges into CSR order
  scatter_kernel<<<2048, 256, 0, stream>>>(row, col, vals, base, cursor, pairs, nnz);
  // 5. SpMM accumulate: one wave per destination
  {
    int wavesPerBlk = 256 / 64;
    int grid = (ndst + wavesPerBlk - 1) / wavesPerBlk;
    spmm_kernel<<<grid, 256, 0, stream>>>(pairs, base, xT, accT, ndst);
  }
  // 6. transpose + bias -> out
  {
    dim3 blk(64, 16);
    int grid = (ndst + 63) / 64;
    write_out_kernel<<<grid, blk, 0, stream>>>(accT, bias, out, ndst);
  }
}